// Round 2
// baseline (30990.042 us; speedup 1.0000x reference)
//
#include <hip/hip_runtime.h>
#include <math.h>

#define T_STEPS 16384
#define IN_DIM  14
#define H_DIM   100
#define G_DIM   300   // 3*H

// LDS float offsets inside each 1024-float buffer.
// H2OFF=132 (not 128): h1 stream hits banks 4k..4k+3, h2 stream banks
// (132+4k)%32 = 4k+4..4k+7 -> disjoint in mixed waves (2-addr broadcast).
#define H1OFF 0      // h1[0..100)
#define H2OFF 132    // h2[0..100)
#define AOFF  256    // a (layer-1 input preacts) [0..300); AOFF+100 is 16B-aligned

typedef float f2 __attribute__((ext_vector_type(2)));
typedef float f4 __attribute__((ext_vector_type(4)));

#define REP25(M) M(0) M(1) M(2) M(3) M(4) M(5) M(6) M(7) M(8) M(9) M(10) M(11) \
                 M(12) M(13) M(14) M(15) M(16) M(17) M(18) M(19) M(20) M(21) M(22) M(23) M(24)

// ---------------- Phase 0: gi0[t][j] = b_ih0[j] + sum_k x[t][k]*w_ih0[j][k] ----------------
__global__ void gi0_kernel(const float* __restrict__ x,
                           const float* __restrict__ w_ih0,
                           const float* __restrict__ b_ih0,
                           float* __restrict__ gi0) {
    int e = blockIdx.x * blockDim.x + threadIdx.x;
    if (e >= T_STEPS * G_DIM) return;
    int t = e / G_DIM;
    int j = e - t * G_DIM;
    const float* xr = x + t * IN_DIM;
    const float* wr = w_ih0 + j * IN_DIM;
    float acc = b_ih0[j];
    #pragma unroll
    for (int k = 0; k < IN_DIM; ++k) acc = fmaf(xr[k], wr[k], acc);
    gi0[e] = acc;
}

// ---------------- Phase 1: persistent single-workgroup sequential GRU ----------------
// ROUND 2: the binding constraint (r0/r1 post-mortem) is LDS return bandwidth:
// every lane receiving the full 100-float h vector costs lanes*400B per step.
// So: 256 threads (4 waves, 1 wave/SIMD -> 512-reg unified VGPR+AGPR budget),
// each lane owns FOUR weight rows (400 floats) as named f2 SSA values.
//   lanes   0- 99: l0 gate j = w_hh0 rows {j, j+100, j+200} + w_ih1 r-row j.
//                  All four rows dot against h1 -> single broadcast stream.
//   lanes 100-199: l1 gate j = w_hh1 rows {j, j+100, j+200} + dup of row j
//                  (4th-row FMAs issue wave-wide regardless; dup costs nothing
//                  and keeps one uniform dot body). Reads h2.
//   lanes 200-249: w_ih1 rows 100+4m..103+4m (z/n preacts), reads h1,
//                  writes a float4 of preacts. lanes 250-255 clone, never write.
// Gates are fully lane-local (r,z,n co-resident): no bpermute handoff.
// LDS read traffic: 100 broadcast ds_read_b128/iter (was 200).
// One __syncthreads per iteration; h1/h2/a double-buffered (bufA/bufB).
// Accumulation patterns and gate formulas are bit-identical to round 1
// (absmax 0.0 preserved). Weight rows MUST stay named f2 SSA values --
// float arrays go to scratch (SROA before unroll).
__global__ __launch_bounds__(256, 1)
void gru_seq_kernel(const float* __restrict__ gi0,
                    const float* __restrict__ w_hh0,
                    const float* __restrict__ b_hh0,
                    const float* __restrict__ w_ih1,
                    const float* __restrict__ b_ih1,
                    const float* __restrict__ w_hh1,
                    const float* __restrict__ b_hh1,
                    const float* __restrict__ fc_w,
                    const float* __restrict__ fc_b,
                    float* __restrict__ out) {
    __shared__ __align__(16) float bufA[1024];
    __shared__ __align__(16) float bufB[1024];

    const int tid = threadIdx.x;

    const float *r0p, *r1p, *r2p, *r3p;
    float b0, b1, b2, b3;
    int hoff4, j;
    if (tid < 100) {                       // l0 gate j + l1in r-row j
        j = tid;
        r0p = w_hh0 + (size_t)j * H_DIM;
        r1p = w_hh0 + (size_t)(j + 100) * H_DIM;
        r2p = w_hh0 + (size_t)(j + 200) * H_DIM;
        r3p = w_ih1 + (size_t)j * H_DIM;
        b0 = b_hh0[j]; b1 = b_hh0[j + 100]; b2 = b_hh0[j + 200]; b3 = b_ih1[j];
        hoff4 = H1OFF / 4;
    } else if (tid < 200) {                // l1 gate j (row3 = dup of row0, d3 unused)
        j = tid - 100;
        r0p = w_hh1 + (size_t)j * H_DIM;
        r1p = w_hh1 + (size_t)(j + 100) * H_DIM;
        r2p = w_hh1 + (size_t)(j + 200) * H_DIM;
        r3p = r0p;
        b0 = b_hh1[j]; b1 = b_hh1[j + 100]; b2 = b_hh1[j + 200]; b3 = 0.0f;
        hoff4 = H2OFF / 4;
    } else {                               // l1in: 4 consecutive w_ih1 rows
        int m = tid - 200; if (m > 49) m = 49;   // 250-255 clone, never write
        j = m;
        r0p = w_ih1 + (size_t)(100 + 4 * m)     * H_DIM;
        r1p = w_ih1 + (size_t)(100 + 4 * m + 1) * H_DIM;
        r2p = w_ih1 + (size_t)(100 + 4 * m + 2) * H_DIM;
        r3p = w_ih1 + (size_t)(100 + 4 * m + 3) * H_DIM;
        b0 = b_ih1[100 + 4 * m];     b1 = b_ih1[100 + 4 * m + 1];
        b2 = b_ih1[100 + 4 * m + 2]; b3 = b_ih1[100 + 4 * m + 3];
        hoff4 = H1OFF / 4;
    }

    // ---- weight registers: 200 named f2 values (400 f32), guaranteed SSA ----
    #define DECLK(k) f2 wa0_##k, wb0_##k, wa1_##k, wb1_##k, wa2_##k, wb2_##k, wa3_##k, wb3_##k;
    REP25(DECLK)
    #undef DECLK
    {
        const f4* p0 = reinterpret_cast<const f4*>(r0p);
        const f4* p1 = reinterpret_cast<const f4*>(r1p);
        const f4* p2 = reinterpret_cast<const f4*>(r2p);
        const f4* p3 = reinterpret_cast<const f4*>(r3p);
        #define LOADK(k) { f4 V; V = p0[k]; wa0_##k = V.lo; wb0_##k = V.hi; \
                           V = p1[k]; wa1_##k = V.lo; wb1_##k = V.hi; \
                           V = p2[k]; wa2_##k = V.lo; wb2_##k = V.hi; \
                           V = p3[k]; wa3_##k = V.lo; wb3_##k = V.hi; }
        REP25(LOADK)
        #undef LOADK
    }

    for (int k = tid; k < 1024; k += 256) { bufA[k] = 0.0f; bufB[k] = 0.0f; }
    __syncthreads();

    // Same pipeline schedule as round 1 (verified): per iteration it,
    // l0 produces h1(it) for it<T; l0/l1in produce a(it-1) for 1<=it<=T;
    // l1 produces h2(it-2) for it>=2. One barrier per iteration.
    for (int it = 0; it < T_STEPS + 2; ++it) {
        float* bc = (it & 1) ? bufB : bufA;   // read buffer (written last iter)
        float* bn = (it & 1) ? bufA : bufB;   // write buffer

        // Prefetch gate inputs + h_old; dot phase covers the latency.
        float gr = 0.f, gz = 0.f, gn = 0.f, hold = 0.f;
        if (tid < 100) {
            if (it < T_STEPS) {
                const float* p = gi0 + (size_t)it * G_DIM + tid;
                gr = p[0]; gz = p[H_DIM]; gn = p[2 * H_DIM];
            }
            hold = bc[H1OFF + tid];
        } else if (tid < 200) {
            gr = bc[AOFF + j];
            gz = bc[AOFF + 100 + j];
            gn = bc[AOFF + 200 + j];
            hold = bc[H2OFF + j];
        }

        // Dot phase: 4 rows x 100, packed-f32 FMAs, broadcast ds_read_b128 of h.
        const f4* hb4 = reinterpret_cast<const f4*>(bc) + hoff4;
        f2 a0A, a0B, a1A, a1B, a2A, a2B, a3A, a3B;
        a0A.x = b0; a0A.y = 0.0f;  a0B.x = 0.0f; a0B.y = 0.0f;
        a1A.x = b1; a1A.y = 0.0f;  a1B.x = 0.0f; a1B.y = 0.0f;
        a2A.x = b2; a2A.y = 0.0f;  a2B.x = 0.0f; a2B.y = 0.0f;
        a3A.x = b3; a3A.y = 0.0f;  a3B.x = 0.0f; a3B.y = 0.0f;
        #define DOTK(k) { f4 V = hb4[k]; f2 lo = V.lo, hi = V.hi; \
                          a0A += wa0_##k * lo; a0B += wb0_##k * hi; \
                          a1A += wa1_##k * lo; a1B += wb1_##k * hi; \
                          a2A += wa2_##k * lo; a2B += wb2_##k * hi; \
                          a3A += wa3_##k * lo; a3B += wb3_##k * hi; }
        REP25(DOTK)
        #undef DOTK
        float d0 = (a0A.x + a0B.x) + (a0A.y + a0B.y);
        float d1 = (a1A.x + a1B.x) + (a1A.y + a1B.y);
        float d2 = (a2A.x + a2B.x) + (a2A.y + a2B.y);
        float d3 = (a3A.x + a3B.x) + (a3A.y + a3B.y);

        if (tid < 100) {
            if (it < T_STEPS) {            // h1(it)
                float r = 1.0f / (1.0f + expf(-(gr + d0)));
                float z = 1.0f / (1.0f + expf(-(gz + d1)));
                float n = tanhf(gn + r * d2);
                bn[H1OFF + tid] = (1.0f - z) * n + z * hold;
            }
            if (it >= 1 && it <= T_STEPS)  // a_r(it-1), uses h1(it-1) from bc
                bn[AOFF + tid] = d3;
        } else if (tid < 200) {
            if (it >= 2) {                 // h2(it-2)
                float r = 1.0f / (1.0f + expf(-(gr + d0)));
                float z = 1.0f / (1.0f + expf(-(gz + d1)));
                float n = tanhf(gn + r * d2);
                bn[H2OFF + j] = (1.0f - z) * n + z * hold;
            }
        } else if (tid < 250 && it >= 1 && it <= T_STEPS) {
            f4 w; w.x = d0; w.y = d1; w.z = d2; w.w = d3;   // a_{z,n}(it-1)
            reinterpret_cast<f4*>(bn + AOFF + 100)[j] = w;
        }
        __syncthreads();
    }

    // FC epilogue: h2(T-1) was written at it=T+1 (odd) -> bufA.
    if (tid < 64) {
        float s = 0.0f;
        for (int k = tid; k < H_DIM; k += 64) s = fmaf(fc_w[k], bufA[H2OFF + k], s);
        #pragma unroll
        for (int off = 32; off > 0; off >>= 1) s += __shfl_down(s, off);
        if (tid == 0) out[0] = s + fc_b[0];
    }
}

extern "C" void kernel_launch(void* const* d_in, const int* in_sizes, int n_in,
                              void* d_out, int out_size, void* d_ws, size_t ws_size,
                              hipStream_t stream) {
    const float* x     = (const float*)d_in[0];
    const float* w_ih0 = (const float*)d_in[1];
    const float* w_hh0 = (const float*)d_in[2];
    const float* b_ih0 = (const float*)d_in[3];
    const float* b_hh0 = (const float*)d_in[4];
    const float* w_ih1 = (const float*)d_in[5];
    const float* w_hh1 = (const float*)d_in[6];
    const float* b_ih1 = (const float*)d_in[7];
    const float* b_hh1 = (const float*)d_in[8];
    const float* fc_w  = (const float*)d_in[9];
    const float* fc_b  = (const float*)d_in[10];
    float* out = (float*)d_out;
    float* gi0 = (float*)d_ws;   // T*300 floats = 19.66 MB

    const int total = T_STEPS * G_DIM;
    gi0_kernel<<<(total + 255) / 256, 256, 0, stream>>>(x, w_ih0, b_ih0, gi0);
    gru_seq_kernel<<<1, 256, 0, stream>>>(gi0, w_hh0, b_hh0, w_ih1, b_ih1,
                                          w_hh1, b_hh1, fc_w, fc_b, out);
}

// Round 3
// 21148.311 us; speedup vs baseline: 1.4654x; 1.4654x over previous
//
#include <hip/hip_runtime.h>
#include <math.h>

#define T_STEPS 16384
#define IN_DIM  14
#define H_DIM   100
#define G_DIM   300   // 3*H

// LDS float offsets inside each 1024-float buffer.
// H2OFF=132: h1 broadcast stream and h2 broadcast stream hit disjoint banks.
#define H1OFF 0      // h1[0..100)
#define H2OFF 132    // h2[0..100)
#define AOFF  256    // a (layer-1 input preacts) [0..300)

typedef float f2 __attribute__((ext_vector_type(2)));
typedef float f4 __attribute__((ext_vector_type(4)));

#define REP25(M) M(0) M(1) M(2) M(3) M(4) M(5) M(6) M(7) M(8) M(9) M(10) M(11) \
                 M(12) M(13) M(14) M(15) M(16) M(17) M(18) M(19) M(20) M(21) M(22) M(23) M(24)

// ---------------- Phase 0: gi0[t][j] = b_ih0[j] + sum_k x[t][k]*w_ih0[j][k] ----------------
__global__ void gi0_kernel(const float* __restrict__ x,
                           const float* __restrict__ w_ih0,
                           const float* __restrict__ b_ih0,
                           float* __restrict__ gi0) {
    int e = blockIdx.x * blockDim.x + threadIdx.x;
    if (e >= T_STEPS * G_DIM) return;
    int t = e / G_DIM;
    int j = e - t * G_DIM;
    const float* xr = x + t * IN_DIM;
    const float* wr = w_ih0 + j * IN_DIM;
    float acc = b_ih0[j];
    #pragma unroll
    for (int k = 0; k < IN_DIM; ++k) acc = fmaf(xr[k], wr[k], acc);
    gi0[e] = acc;
}

// ---------------- Phase 1: persistent single-workgroup sequential GRU ----------------
// ROUND 3. Post-mortem facts: per-iter time scales as 1/(waves per SIMD)
// (R1: 2 w/SIMD = 2270 cyc; R2: 1 w/SIMD = 4560 cyc) and is insensitive to
// per-lane FMA count -> the cost is per-wave EXPOSED LDS LATENCY (25
// dependent ds_read_b128 -> FMA groups, no prefetch depth due to register
// pressure), divided by wave overlap. So: maximize waves/SIMD.
//   1024 threads = 16 waves = 4 waves/SIMD (VGPR cap 128).
//   Each active lane owns ONE 100-float weight row (100 VGPRs as 50 named
//   f2 SSA values; arrays would hit scratch). ~25 spare regs let the
//   scheduler keep several ds_reads in flight.
// Wave layout (waves 0-4: w_hh0/l0, 5-9: w_hh1/l1, 10-14: w_ih1/l1in,
// 15: idle at barrier). Within a wave: lanes 0-19 r-rows of gates
// gbase..gbase+19, lanes 20-39 z-rows, lanes 40-59 n-rows, 60-63 clones.
// Gate combine: two intra-wave ds_bpermute pull z-dot/n-dot to the r-lane,
// which computes sigmoid/sigmoid/tanh and writes h. No extra barrier.
// Pipeline schedule unchanged from R1/R2 (verified): at iter it, l0 makes
// h1(it) [it<T], l1in makes a(it-1) [1<=it<=T], l1 makes h2(it-2) [it>=2];
// ONE __syncthreads per iteration; h1/h2/a double-buffered (bufA/bufB).
// Per-row accumulation (lo/hi f2 chains + same final reduce) and gate
// formulas bit-identical to R1/R2 -> absmax 0.0 preserved.
__global__ __launch_bounds__(1024, 4)
void gru_seq_kernel(const float* __restrict__ gi0,
                    const float* __restrict__ w_hh0,
                    const float* __restrict__ b_hh0,
                    const float* __restrict__ w_ih1,
                    const float* __restrict__ b_ih1,
                    const float* __restrict__ w_hh1,
                    const float* __restrict__ b_hh1,
                    const float* __restrict__ fc_w,
                    const float* __restrict__ fc_b,
                    float* __restrict__ out) {
    __shared__ __align__(16) float bufA[1024];
    __shared__ __align__(16) float bufB[1024];

    const int tid = threadIdx.x;
    const int wave = tid >> 6;
    const int ln = tid & 63;

    int grp, gbase;
    if (wave < 5)       { grp = 0; gbase = wave * 20; }
    else if (wave < 10) { grp = 1; gbase = (wave - 5) * 20; }
    else if (wave < 15) { grp = 2; gbase = (wave - 10) * 20; }
    else                { grp = 3; gbase = 0; }

    const int ln20 = ln % 20;           // partner/slot index 0..19
    const int role = ln / 20;           // 0=r, 1=z, 2=n, 3=clone
    const int roleC = (role > 2) ? 2 : role;
    const int q = gbase + ln20;         // gate / column-slot id 0..99
    const int row = roleC * 100 + q;    // weight row 0..299
    const bool isR = (role == 0);

    const float* wm; const float* bm;
    if (grp == 0)      { wm = w_hh0; bm = b_hh0; }
    else if (grp == 1) { wm = w_hh1; bm = b_hh1; }
    else if (grp == 2) { wm = w_ih1; bm = b_ih1; }
    else               { wm = w_hh0; bm = b_hh0; }   // wave 15: dummy row 0
    const int rowE = (grp == 3) ? 0 : row;
    const float bias = (grp == 3) ? 0.0f : bm[rowE];
    const int hoff  = (grp == 1) ? H2OFF : H1OFF;
    const int hoff4 = hoff / 4;

    // bpermute byte-addresses of this r-lane's z/n partners (garbage for
    // non-r lanes, never used there).
    const int adZ = (20 + ln20) << 2;
    const int adN = (40 + ln20) << 2;

    // ---- weight row: 50 named f2 values (100 f32), guaranteed SSA ----
    #define DECLK(k) f2 wa_##k, wb_##k;
    REP25(DECLK)
    #undef DECLK
    {
        const f4* p = reinterpret_cast<const f4*>(wm + (size_t)rowE * H_DIM);
        #define LOADK(k) { f4 V = p[k]; wa_##k = V.lo; wb_##k = V.hi; }
        REP25(LOADK)
        #undef LOADK
    }

    for (int k = tid; k < 1024; k += 1024) { }   // (no-op; keep tid usage obvious)
    if (tid < 1024) { bufA[tid] = 0.0f; bufB[tid] = 0.0f; }
    __syncthreads();

    for (int it = 0; it < T_STEPS + 2; ++it) {
        float* bc = (it & 1) ? bufB : bufA;   // read buffer (written last iter)
        float* bn = (it & 1) ? bufA : bufB;   // write buffer

        if (grp < 3) {
            // Prefetch gate inputs + h_old (r-lanes only); dots cover latency.
            float g_r = 0.f, g_z = 0.f, g_n = 0.f, hold = 0.f;
            if (grp == 0) {
                if (isR && it < T_STEPS) {
                    const float* p = gi0 + (size_t)it * G_DIM + q;
                    g_r = p[0]; g_z = p[H_DIM]; g_n = p[2 * H_DIM];
                }
                if (isR) hold = bc[H1OFF + q];
            } else if (grp == 1) {
                if (isR) {
                    g_r  = bc[AOFF + q];
                    g_z  = bc[AOFF + 100 + q];
                    g_n  = bc[AOFF + 200 + q];
                    hold = bc[H2OFF + q];
                }
            }

            // Dot: 1 row x 100, broadcast ds_read_b128 of h, lo/hi f2 chains.
            const f4* hb4 = reinterpret_cast<const f4*>(bc) + hoff4;
            f2 accA, accB;
            accA.x = bias; accA.y = 0.0f;
            accB.x = 0.0f; accB.y = 0.0f;
            #define DOTK(k) { f4 V = hb4[k]; accA += wa_##k * V.lo; accB += wb_##k * V.hi; }
            REP25(DOTK)
            #undef DOTK
            float d = (accA.x + accB.x) + (accA.y + accB.y);

            if (grp <= 1) {
                // Pull z-dot and n-dot to the r-lane (intra-wave, all lanes
                // execute so sources are active).
                float dz = __int_as_float(__builtin_amdgcn_ds_bpermute(adZ, __float_as_int(d)));
                float dn = __int_as_float(__builtin_amdgcn_ds_bpermute(adN, __float_as_int(d)));
                bool act = isR && ((grp == 0) ? (it < T_STEPS) : (it >= 2));
                if (act) {
                    float r = 1.0f / (1.0f + expf(-(g_r + d)));
                    float z = 1.0f / (1.0f + expf(-(g_z + dz)));
                    float n = tanhf(g_n + r * dn);
                    bn[hoff + q] = (1.0f - z) * n + z * hold;
                }
            } else {
                // l1in: write a(it-1) preact (bias already in d)
                if (role < 3 && it >= 1 && it <= T_STEPS) bn[AOFF + row] = d;
            }
        }
        __syncthreads();
    }

    // FC epilogue: h2(T-1) written at it = T+1 (odd) -> bufA.
    if (tid < 64) {
        float s = 0.0f;
        for (int k = tid; k < H_DIM; k += 64) s = fmaf(fc_w[k], bufA[H2OFF + k], s);
        #pragma unroll
        for (int off = 32; off > 0; off >>= 1) s += __shfl_down(s, off);
        if (tid == 0) out[0] = s + fc_b[0];
    }
}

extern "C" void kernel_launch(void* const* d_in, const int* in_sizes, int n_in,
                              void* d_out, int out_size, void* d_ws, size_t ws_size,
                              hipStream_t stream) {
    const float* x     = (const float*)d_in[0];
    const float* w_ih0 = (const float*)d_in[1];
    const float* w_hh0 = (const float*)d_in[2];
    const float* b_ih0 = (const float*)d_in[3];
    const float* b_hh0 = (const float*)d_in[4];
    const float* w_ih1 = (const float*)d_in[5];
    const float* w_hh1 = (const float*)d_in[6];
    const float* b_ih1 = (const float*)d_in[7];
    const float* b_hh1 = (const float*)d_in[8];
    const float* fc_w  = (const float*)d_in[9];
    const float* fc_b  = (const float*)d_in[10];
    float* out = (float*)d_out;
    float* gi0 = (float*)d_ws;   // T*300 floats = 19.66 MB

    const int total = T_STEPS * G_DIM;
    gi0_kernel<<<(total + 255) / 256, 256, 0, stream>>>(x, w_ih0, b_ih0, gi0);
    gru_seq_kernel<<<1, 1024, 0, stream>>>(gi0, w_hh0, b_hh0, w_ih1, b_ih1,
                                           w_hh1, b_hh1, fc_w, fc_b, out);
}

// Round 4
// 20723.817 us; speedup vs baseline: 1.4954x; 1.0205x over previous
//
#include <hip/hip_runtime.h>
#include <math.h>
#include <limits.h>

#define T_STEPS 16384
#define IN_DIM  14
#define H_DIM   100
#define G_DIM   300   // 3*H

// LDS float offsets inside each 1024-float buffer (same as R3).
#define H1OFF 0      // h1[0..100)   (WG0)
#define H2OFF 132    // h2[0..100)   (WG1)
#define AOFF  256    // a = w_ih1.h1 preacts [0..300)  (WG1)

typedef float f2 __attribute__((ext_vector_type(2)));
typedef float f4 __attribute__((ext_vector_type(4)));

#define REP25(M) M(0) M(1) M(2) M(3) M(4) M(5) M(6) M(7) M(8) M(9) M(10) M(11) \
                 M(12) M(13) M(14) M(15) M(16) M(17) M(18) M(19) M(20) M(21) M(22) M(23) M(24)

// ---------------- Phase 0: gi0[t][j] = b_ih0[j] + sum_k x[t][k]*w_ih0[j][k] ----------------
__global__ void gi0_kernel(const float* __restrict__ x,
                           const float* __restrict__ w_ih0,
                           const float* __restrict__ b_ih0,
                           float* __restrict__ gi0) {
    int e = blockIdx.x * blockDim.x + threadIdx.x;
    if (e >= T_STEPS * G_DIM) return;
    int t = e / G_DIM;
    int j = e - t * G_DIM;
    const float* xr = x + t * IN_DIM;
    const float* wr = w_ih0 + j * IN_DIM;
    float acc = b_ih0[j];
    #pragma unroll
    for (int k = 0; k < IN_DIM; ++k) acc = fmaf(xr[k], wr[k], acc);
    gi0[e] = acc;
}

// ---------------- Phase 1: TWO persistent workgroups (one CU per GRU layer) ----------------
// ROUND 4 root cause (from VGPR_Count history 128/120/224/64 vs plans needing
// 200/200/400/100 floats/lane): weight "registers" NEVER fit architectural
// VGPRs; the compiler demoted them to AGPRs, costing ~1 v_accvgpr_read per
// dword per iteration (~3x the pure-FMA VALU work — matches measured
// VALUBusy every round). 90K weight floats cannot fit one CU's file with
// working margins, so: split layers across TWO blocks on TWO CUs.
//   WG0 (block 0): layer-0 recurrence. waves 0-4 = R3's verified gate layout
//     over w_hh0 (1 row/lane, 100 fl = 50 named f2; lanes 0-19 r, 20-39 z,
//     40-59 n, 60-63 clones; bpermute combine). wave 5 = gi0->LDS ring
//     prefetch (2 ahead). wave 6 = h1 publisher -> global + chunked flag.
//   WG1 (block 1): layer 1. waves 0-4 = gate layout over w_hh1 (reads h2);
//     waves 5-9 = w_ih1 rows (1 row/lane) computing a(t) from h1; wave 10 =
//     h1 prefetcher (global ring -> LDS ring, 2 steps ahead, flag-gated).
// Block = 704 threads = 11 waves -> 3 waves/SIMD -> VGPR cap 170:
// 100 weight floats + ~35 working TRULY fits. No AGPR tax.
// Handoff: h1 history in workspace (full T buffer when ws allows -> WG0
// never waits -> deadlock-free even if blocks serialize). Agent-scope
// atomics for data+flags (cross-XCD safe). WG1 stages h1 into LDS 2 steps
// ahead so cross-CU latency stays off the serial chain.
// All accumulation chains/reduce order/gate math verbatim from R3 ->
// bit-identical results (absmax 0.0 preserved).
__global__ __launch_bounds__(704, 3)
void gru2_kernel(const float* __restrict__ gi0,
                 const float* __restrict__ w_hh0, const float* __restrict__ b_hh0,
                 const float* __restrict__ w_ih1, const float* __restrict__ b_ih1,
                 const float* __restrict__ w_hh1, const float* __restrict__ b_hh1,
                 const float* __restrict__ fc_w,  const float* __restrict__ fc_b,
                 float* __restrict__ out,
                 float* __restrict__ h1g, int* flags, int rmask, int bp_limit) {
    __shared__ __align__(16) float bufA[1024];
    __shared__ __align__(16) float bufB[1024];
    __shared__ __align__(16) float giring[4 * 304];  // 4-slot ring of gi0 rows (WG0)
    __shared__ __align__(16) float h1ring[4 * 128];  // 4-slot ring of h1 steps (WG1)

    const int tid  = threadIdx.x;
    const int wave = tid >> 6;
    const int ln   = tid & 63;
    int* prodp = flags;        // produced chunks (8 steps each), set by WG0
    int* consp = flags + 32;   // consumed chunks, set by WG1 (128B apart)

    for (int k = tid; k < 1024; k += 704) { bufA[k] = 0.0f; bufB[k] = 0.0f; }
    __syncthreads();

    // Common intra-wave gate-layout constants (meaningful for gate waves).
    const int ln20  = ln % 20;
    const int role  = ln / 20;                 // 0=r, 1=z, 2=n, 3=clone
    const int roleC = (role > 2) ? 2 : role;
    const bool isR  = (role == 0);
    const int adZ   = (20 + ln20) << 2;        // bpermute byte addr of z-partner
    const int adN   = (40 + ln20) << 2;        // bpermute byte addr of n-partner

    if (blockIdx.x == 0) {
        // =================== WG0: layer-0 recurrence ===================
        const int q = wave * 20 + ln20;        // gate id (valid for wave<5)

        #define DECLK(k) f2 wa_##k, wb_##k;
        REP25(DECLK)
        #undef DECLK
        float bias = 0.0f;
        if (wave < 5) {
            const int row = roleC * 100 + q;
            bias = b_hh0[row];
            const f4* p = reinterpret_cast<const f4*>(w_hh0 + (size_t)row * H_DIM);
            #define LOADK(k) { f4 V = p[k]; wa_##k = V.lo; wb_##k = V.hi; }
            REP25(LOADK)
            #undef LOADK
        }

        // prologue: gi0 rows 0,1 -> ring slots 0,1
        if (wave == 5) {
            #pragma unroll
            for (int r = 0; r < 2; ++r) {
                const f4* src = reinterpret_cast<const f4*>(gi0 + (size_t)r * G_DIM);
                f4* dst = reinterpret_cast<f4*>(giring + r * 304);
                dst[ln] = src[ln];
                if (ln < 11) dst[64 + ln] = src[64 + ln];
            }
        }
        __syncthreads();

        int cons_c = 0;  // cached consumed-steps (backpressure; unused when bp_limit=INT_MAX)
        for (int t = 0; t <= T_STEPS; ++t) {
            float* bc = (t & 1) ? bufB : bufA;
            float* bn = (t & 1) ? bufA : bufB;

            if (wave < 5) {
                float g_r = 0.f, g_z = 0.f, g_n = 0.f, hold = 0.f;
                if (isR) {
                    if (t < T_STEPS) {
                        const float* gi = giring + (t & 3) * 304;
                        g_r = gi[q]; g_z = gi[100 + q]; g_n = gi[200 + q];
                    }
                    hold = bc[H1OFF + q];
                }
                const f4* hb4 = reinterpret_cast<const f4*>(bc + H1OFF);
                f2 accA, accB;
                accA.x = bias; accA.y = 0.0f; accB.x = 0.0f; accB.y = 0.0f;
                #define DOTK(k) { f4 V = hb4[k]; accA += wa_##k * V.lo; accB += wb_##k * V.hi; }
                REP25(DOTK)
                #undef DOTK
                float d = (accA.x + accB.x) + (accA.y + accB.y);
                float dz = __int_as_float(__builtin_amdgcn_ds_bpermute(adZ, __float_as_int(d)));
                float dn = __int_as_float(__builtin_amdgcn_ds_bpermute(adN, __float_as_int(d)));
                if (isR && t < T_STEPS) {
                    float r = 1.0f / (1.0f + expf(-(g_r + d)));
                    float z = 1.0f / (1.0f + expf(-(g_z + dz)));
                    float n = tanhf(g_n + r * dn);
                    bn[H1OFF + q] = (1.0f - z) * n + z * hold;
                }
            } else if (wave == 5) {
                // prefetch gi0 row t+2 into ring slot (t+2)&3
                const int r = t + 2;
                if (r <= T_STEPS - 1) {
                    const f4* src = reinterpret_cast<const f4*>(gi0 + (size_t)r * G_DIM);
                    f4* dst = reinterpret_cast<f4*>(giring + (r & 3) * 304);
                    f4 v0 = src[ln];
                    dst[ln] = v0;
                    if (ln < 11) { f4 v1 = src[64 + ln]; dst[64 + ln] = v1; }
                }
            } else if (wave == 6) {
                // publish h1(t-1) (in bc) to global + chunk flag every 8 steps
                if (t >= 1) {
                    const int e = t - 1;
                    while (e - cons_c >= bp_limit)
                        cons_c = 8 * __hip_atomic_load(consp, __ATOMIC_ACQUIRE, __HIP_MEMORY_SCOPE_AGENT);
                    float* dstb = h1g + (size_t)(e & rmask) * H_DIM;
                    float v0 = bc[H1OFF + ln];
                    __hip_atomic_store(dstb + ln, v0, __ATOMIC_RELAXED, __HIP_MEMORY_SCOPE_AGENT);
                    if (ln < 36) {
                        float v1 = bc[H1OFF + 64 + ln];
                        __hip_atomic_store(dstb + 64 + ln, v1, __ATOMIC_RELAXED, __HIP_MEMORY_SCOPE_AGENT);
                    }
                    if ((t & 7) == 0) {
                        __threadfence();                       // drain this wave's stores
                        if (ln == 0)
                            __hip_atomic_store(prodp, t >> 3, __ATOMIC_RELEASE, __HIP_MEMORY_SCOPE_AGENT);
                    }
                }
            }
            __syncthreads();
        }
    } else {
        // =================== WG1: layer-1 recurrence + input projection ===================
        const int q = wave * 20 + ln20;        // gate id (valid for wave<5)
        const int s = tid - 320;               // ih1 row space (waves 5-9: 0..319)
        const int rowI = (s < 0) ? 0 : ((s > 299) ? 299 : s);

        #define DECLK(k) f2 wa_##k, wb_##k;
        REP25(DECLK)
        #undef DECLK
        float bias = 0.0f;
        if (wave < 5) {
            const int row = roleC * 100 + q;
            bias = b_hh1[row];
            const f4* p = reinterpret_cast<const f4*>(w_hh1 + (size_t)row * H_DIM);
            #define LOADK(k) { f4 V = p[k]; wa_##k = V.lo; wb_##k = V.hi; }
            REP25(LOADK)
            #undef LOADK
        } else if (wave < 10) {
            bias = b_ih1[rowI];
            const f4* p = reinterpret_cast<const f4*>(w_ih1 + (size_t)rowI * H_DIM);
            #define LOADK(k) { f4 V = p[k]; wa_##k = V.lo; wb_##k = V.hi; }
            REP25(LOADK)
            #undef LOADK
        }

        int prod_c = 0;  // cached produced-steps
        // prologue: h1(0) -> LDS ring slot 0 (flag-gated)
        if (wave == 10) {
            while (prod_c <= 0)
                prod_c = 8 * __hip_atomic_load(prodp, __ATOMIC_ACQUIRE, __HIP_MEMORY_SCOPE_AGENT);
            float v0 = __hip_atomic_load(h1g + ln, __ATOMIC_RELAXED, __HIP_MEMORY_SCOPE_AGENT);
            h1ring[ln] = v0;
            if (ln < 36) {
                float v1 = __hip_atomic_load(h1g + 64 + ln, __ATOMIC_RELAXED, __HIP_MEMORY_SCOPE_AGENT);
                h1ring[64 + ln] = v1;
            }
        }
        __syncthreads();

        for (int k = 0; k <= T_STEPS + 1; ++k) {
            float* bc = (k & 1) ? bufB : bufA;
            float* bn = (k & 1) ? bufA : bufB;

            if (wave < 5) {
                // h2(k-2) = f(h2(k-3), a(k-2))   [same schedule as R3 l1]
                float g_r = 0.f, g_z = 0.f, g_n = 0.f, hold = 0.f;
                if (isR) {
                    g_r  = bc[AOFF + q];
                    g_z  = bc[AOFF + 100 + q];
                    g_n  = bc[AOFF + 200 + q];
                    hold = bc[H2OFF + q];
                }
                const f4* hb4 = reinterpret_cast<const f4*>(bc + H2OFF);
                f2 accA, accB;
                accA.x = bias; accA.y = 0.0f; accB.x = 0.0f; accB.y = 0.0f;
                #define DOTK(k) { f4 V = hb4[k]; accA += wa_##k * V.lo; accB += wb_##k * V.hi; }
                REP25(DOTK)
                #undef DOTK
                float d = (accA.x + accB.x) + (accA.y + accB.y);
                float dz = __int_as_float(__builtin_amdgcn_ds_bpermute(adZ, __float_as_int(d)));
                float dn = __int_as_float(__builtin_amdgcn_ds_bpermute(adN, __float_as_int(d)));
                if (isR && k >= 2) {
                    float r = 1.0f / (1.0f + expf(-(g_r + d)));
                    float z = 1.0f / (1.0f + expf(-(g_z + dz)));
                    float n = tanhf(g_n + r * dn);
                    bn[H2OFF + q] = (1.0f - z) * n + z * hold;
                }
            } else if (wave < 10) {
                // a(k-1) = b_ih1 + w_ih1 . h1(k-1)  (h1 from LDS ring)
                if (k >= 1 && k <= T_STEPS) {
                    const f4* hb4 = reinterpret_cast<const f4*>(h1ring + ((k - 1) & 3) * 128);
                    f2 accA, accB;
                    accA.x = bias; accA.y = 0.0f; accB.x = 0.0f; accB.y = 0.0f;
                    #define DOTK(k) { f4 V = hb4[k]; accA += wa_##k * V.lo; accB += wb_##k * V.hi; }
                    REP25(DOTK)
                    #undef DOTK
                    float d = (accA.x + accB.x) + (accA.y + accB.y);
                    if (s < 300) bn[AOFF + s] = d;
                }
            } else {
                // wave 10: prefetch h1(k+1) -> ring slot (k+1)&3 (2 ahead of reader)
                const int e = k + 1;
                if (e <= T_STEPS - 1) {
                    while (prod_c <= e)
                        prod_c = 8 * __hip_atomic_load(prodp, __ATOMIC_ACQUIRE, __HIP_MEMORY_SCOPE_AGENT);
                    const float* srcb = h1g + (size_t)(e & rmask) * H_DIM;
                    float* dst = h1ring + (e & 3) * 128;
                    float v0 = __hip_atomic_load(srcb + ln, __ATOMIC_RELAXED, __HIP_MEMORY_SCOPE_AGENT);
                    dst[ln] = v0;
                    if (ln < 36) {
                        float v1 = __hip_atomic_load(srcb + 64 + ln, __ATOMIC_RELAXED, __HIP_MEMORY_SCOPE_AGENT);
                        dst[64 + ln] = v1;
                    }
                }
                if ((k & 7) == 7 && ln == 0)
                    __hip_atomic_store(consp, (k + 1) >> 3, __ATOMIC_RELAXED, __HIP_MEMORY_SCOPE_AGENT);
            }
            __syncthreads();
        }
    }

    // FC epilogue (WG1): h2(T-1) written at k=T+1 (odd) -> bufA.
    if (blockIdx.x == 1 && tid < 64) {
        float sacc = 0.0f;
        for (int j = tid; j < H_DIM; j += 64) sacc = fmaf(fc_w[j], bufA[H2OFF + j], sacc);
        #pragma unroll
        for (int off = 32; off > 0; off >>= 1) sacc += __shfl_down(sacc, off);
        if (tid == 0) out[0] = sacc + fc_b[0];
    }
}

extern "C" void kernel_launch(void* const* d_in, const int* in_sizes, int n_in,
                              void* d_out, int out_size, void* d_ws, size_t ws_size,
                              hipStream_t stream) {
    const float* x     = (const float*)d_in[0];
    const float* w_ih0 = (const float*)d_in[1];
    const float* w_hh0 = (const float*)d_in[2];
    const float* b_ih0 = (const float*)d_in[3];
    const float* b_hh0 = (const float*)d_in[4];
    const float* w_ih1 = (const float*)d_in[5];
    const float* w_hh1 = (const float*)d_in[6];
    const float* b_ih1 = (const float*)d_in[7];
    const float* b_hh1 = (const float*)d_in[8];
    const float* fc_w  = (const float*)d_in[9];
    const float* fc_b  = (const float*)d_in[10];
    float* out = (float*)d_out;

    float* gi0 = (float*)d_ws;                                   // 19.66 MB
    const size_t gi0_bytes = (size_t)T_STEPS * G_DIM * sizeof(float);
    const size_t full_h1   = (size_t)T_STEPS * H_DIM * sizeof(float);  // 6.55 MB

    // Full h1 history when workspace allows (WG0 never waits -> deadlock-free
    // even without co-residency). Fallback: 2048-step ring with backpressure
    // (needs co-residency; 2 blocks on a 256-CU idle GPU co-run).
    int ring, bp;
    if (ws_size >= gi0_bytes + full_h1 + 256) { ring = T_STEPS; bp = INT_MAX; }
    else                                      { ring = 2048;    bp = 2048 - 64; }

    float* h1g = (float*)((char*)d_ws + gi0_bytes);
    int* flags = (int*)((char*)d_ws + gi0_bytes + (size_t)ring * H_DIM * sizeof(float));
    hipMemsetAsync(flags, 0, 256, stream);   // reset produced/consumed each launch

    const int total = T_STEPS * G_DIM;
    gi0_kernel<<<(total + 255) / 256, 256, 0, stream>>>(x, w_ih0, b_ih0, gi0);
    gru2_kernel<<<2, 704, 0, stream>>>(gi0, w_hh0, b_hh0, w_ih1, b_ih1,
                                       w_hh1, b_hh1, fc_w, fc_b, out,
                                       h1g, flags, ring - 1, bp);
}